// Round 2
// baseline (352.216 us; speedup 1.0000x reference)
//
#include <hip/hip_runtime.h>
#include <math.h>

namespace {
constexpr int NB = 256;   // batch
constexpr int NR = 1152;  // routes (input capsules)
constexpr int NC = 10;    // output capsules
constexpr int NO = 16;    // output dim
constexpr int NI = 8;     // input dim
}

// b = 0, c = 1/R  (softmax of zeros over R)
__global__ __launch_bounds__(256) void k_init(float* __restrict__ bbuf,
                                              float* __restrict__ cbuf) {
    int i = blockIdx.x * 256 + threadIdx.x;
    if (i < NR * NC) { bbuf[i] = 0.0f; cbuf[i] = 1.0f / NR; }
}

// xT[r][b][i] = x[b][r][i]
__global__ __launch_bounds__(256) void k_transpose(const float* __restrict__ x,
                                                   float* __restrict__ xT) {
    int r = blockIdx.x;
    int b = threadIdx.x;
    const float4* src = reinterpret_cast<const float4*>(x + ((size_t)b * NR + r) * NI);
    float4*       dst = reinterpret_cast<float4*>(xT + ((size_t)r * NB + b) * NI);
    dst[0] = src[0];
    dst[1] = src[1];
}

// part[c][ch][b][o] = sum_{r in chunk} c[r,c] * sum_i W[r,c,o,i] * x[b,r,i]
// lane = bg (4 batches each), wave = og (4 outputs each). W via scalar loads.
__global__ __launch_bounds__(256) void k_partial(const float* __restrict__ xT,
                                                 const float* __restrict__ W,
                                                 const float* __restrict__ cbuf,
                                                 float* __restrict__ part,
                                                 int nchunk, int rch) {
    const int c   = blockIdx.x;
    const int ch  = blockIdx.y;
    const int r0  = ch * rch;
    const int tid = threadIdx.x;
    const int bg  = tid & 63;
    const int og  = __builtin_amdgcn_readfirstlane(tid >> 6);  // wave-uniform

    float acc[4][4];
    #pragma unroll
    for (int k = 0; k < 4; ++k)
        #pragma unroll
        for (int oo = 0; oo < 4; ++oo) acc[k][oo] = 0.0f;

    const float* xbase = xT + (size_t)r0 * NB * NI + (size_t)bg * 4 * NI;
    const float* wbase = W + (((size_t)r0 * NC + c) * NO + (size_t)og * 4) * NI;

    for (int rr = 0; rr < rch; ++rr) {
        const int r = r0 + rr;
        // x: this lane's 4 batches, 8 i each (contiguous 128B)
        float4 xv[8];
        const float4* xp = reinterpret_cast<const float4*>(xbase + (size_t)rr * NB * NI);
        #pragma unroll
        for (int j = 0; j < 8; ++j) xv[j] = xp[j];
        // W: wave-uniform 4 o x 8 i -> scalar loads into SGPRs
        float w[32];
        const float* wp = wbase + (size_t)rr * NC * NO * NI;
        #pragma unroll
        for (int j = 0; j < 32; ++j) w[j] = wp[j];
        float cr = cbuf[r * NC + c];   // uniform -> s_load

        #pragma unroll
        for (int k = 0; k < 4; ++k) {
            float4 xa = xv[k * 2], xb = xv[k * 2 + 1];
            #pragma unroll
            for (int oo = 0; oo < 4; ++oo) {
                const float* wo = &w[oo * 8];
                float dot = wo[0] * xa.x + wo[1] * xa.y + wo[2] * xa.z + wo[3] * xa.w
                          + wo[4] * xb.x + wo[5] * xb.y + wo[6] * xb.z + wo[7] * xb.w;
                acc[k][oo] += cr * dot;
            }
        }
    }

    float* pp = part + (((size_t)c * nchunk + ch) * NB + (size_t)bg * 4) * NO + og * 4;
    #pragma unroll
    for (int k = 0; k < 4; ++k)
        *reinterpret_cast<float4*>(pp + (size_t)k * NO) =
            make_float4(acc[k][0], acc[k][1], acc[k][2], acc[k][3]);
}

// s[c,b,o] = sum_ch part ; v = squash(s); vbuf[c][b][o] or out[b][c][o]
__global__ __launch_bounds__(256) void k_reduce(const float* __restrict__ part,
                                                float* __restrict__ vbuf,
                                                float* __restrict__ out,
                                                int nchunk, int final_pass) {
    int gid = blockIdx.x * 256 + threadIdx.x;   // gid=(c*NB+b)*NO+o
    int o  = gid & 15;
    int cb = gid >> 4;
    int b  = cb & 255;
    int c  = cb >> 8;
    float s = 0.0f;
    const float* p = part + ((size_t)c * nchunk * NB + b) * NO + o;
    for (int ch = 0; ch < nchunk; ++ch) s += p[(size_t)ch * NB * NO];
    float v = s * fabsf(s) / (1.0f + s * s);
    if (final_pass) {
        out[((size_t)b * NC + c) * NO + o] = v;
    } else {
        vbuf[gid] = v;
    }
}

// bbuf[r,c] += (1/B) * sum_b sum_o (sum_i W[r,c,o,i] x[b,r,i]) * v[c,b,o]
__global__ __launch_bounds__(256) void k_agree(const float* __restrict__ xT,
                                               const float* __restrict__ W,
                                               const float* __restrict__ vbuf,
                                               float* __restrict__ bbuf,
                                               int rch) {
    const int c   = blockIdx.x;
    const int r0  = blockIdx.y * rch;
    const int tid = threadIdx.x;
    const int bg  = tid & 63;
    const int og  = __builtin_amdgcn_readfirstlane(tid >> 6);

    __shared__ float red[4][64];   // [og][rr], rch <= 64

    // this lane's v: 4 batches x 4 outputs
    float4 vv[4];
    #pragma unroll
    for (int k = 0; k < 4; ++k)
        vv[k] = *reinterpret_cast<const float4*>(
            vbuf + ((size_t)c * NB + (size_t)bg * 4 + k) * NO + og * 4);

    const float* xbase = xT + (size_t)r0 * NB * NI + (size_t)bg * 4 * NI;
    const float* wbase = W + (((size_t)r0 * NC + c) * NO + (size_t)og * 4) * NI;

    for (int rr = 0; rr < rch; ++rr) {
        float4 xv[8];
        const float4* xp = reinterpret_cast<const float4*>(xbase + (size_t)rr * NB * NI);
        #pragma unroll
        for (int j = 0; j < 8; ++j) xv[j] = xp[j];
        float w[32];
        const float* wp = wbase + (size_t)rr * NC * NO * NI;
        #pragma unroll
        for (int j = 0; j < 32; ++j) w[j] = wp[j];

        float p = 0.0f;
        #pragma unroll
        for (int k = 0; k < 4; ++k) {
            float4 xa = xv[k * 2], xb = xv[k * 2 + 1];
            float4 vk = vv[k];
            const float* w0 = &w[0];
            float d0 = w0[0]*xa.x + w0[1]*xa.y + w0[2]*xa.z + w0[3]*xa.w
                     + w0[4]*xb.x + w0[5]*xb.y + w0[6]*xb.z + w0[7]*xb.w;
            const float* w1 = &w[8];
            float d1 = w1[0]*xa.x + w1[1]*xa.y + w1[2]*xa.z + w1[3]*xa.w
                     + w1[4]*xb.x + w1[5]*xb.y + w1[6]*xb.z + w1[7]*xb.w;
            const float* w2 = &w[16];
            float d2 = w2[0]*xa.x + w2[1]*xa.y + w2[2]*xa.z + w2[3]*xa.w
                     + w2[4]*xb.x + w2[5]*xb.y + w2[6]*xb.z + w2[7]*xb.w;
            const float* w3 = &w[24];
            float d3 = w3[0]*xa.x + w3[1]*xa.y + w3[2]*xa.z + w3[3]*xa.w
                     + w3[4]*xb.x + w3[5]*xb.y + w3[6]*xb.z + w3[7]*xb.w;
            p += d0 * vk.x + d1 * vk.y + d2 * vk.z + d3 * vk.w;
        }
        // reduce over 64 lanes (sum over all 256 batches for this wave's 4 o)
        p += __shfl_xor(p, 1);
        p += __shfl_xor(p, 2);
        p += __shfl_xor(p, 4);
        p += __shfl_xor(p, 8);
        p += __shfl_xor(p, 16);
        p += __shfl_xor(p, 32);
        if (bg == 0) red[og][rr] = p;
    }
    __syncthreads();
    if (tid < rch) {
        float a = red[0][tid] + red[1][tid] + red[2][tid] + red[3][tid];
        bbuf[(r0 + tid) * NC + c] += a * (1.0f / NB);
    }
}

// softmax over r (axis 0) per column c
__global__ __launch_bounds__(256) void k_softmax(const float* __restrict__ bbuf,
                                                 float* __restrict__ cbuf) {
    const int c   = blockIdx.x;
    const int tid = threadIdx.x;
    __shared__ float sred[4];
    __shared__ float sred2[4];
    int wave = tid >> 6, lane = tid & 63;

    float m = -1e30f;
    for (int r = tid; r < NR; r += 256) m = fmaxf(m, bbuf[r * NC + c]);
    #pragma unroll
    for (int off = 1; off < 64; off <<= 1) m = fmaxf(m, __shfl_xor(m, off));
    if (lane == 0) sred[wave] = m;
    __syncthreads();
    m = fmaxf(fmaxf(sred[0], sred[1]), fmaxf(sred[2], sred[3]));

    float s = 0.0f;
    for (int r = tid; r < NR; r += 256) {
        float e = expf(bbuf[r * NC + c] - m);
        cbuf[r * NC + c] = e;
        s += e;
    }
    #pragma unroll
    for (int off = 1; off < 64; off <<= 1) s += __shfl_xor(s, off);
    if (lane == 0) sred2[wave] = s;
    __syncthreads();
    s = sred2[0] + sred2[1] + sred2[2] + sred2[3];
    float inv = 1.0f / s;
    for (int r = tid; r < NR; r += 256) cbuf[r * NC + c] *= inv;
}

extern "C" void kernel_launch(void* const* d_in, const int* in_sizes, int n_in,
                              void* d_out, int out_size, void* d_ws, size_t ws_size,
                              hipStream_t stream) {
    const float* x = (const float*)d_in[0];   // [256,1152,8]
    const float* W = (const float*)d_in[1];   // [1152,10,16,8]
    float* out = (float*)d_out;               // [256,10,16,1]

    // choose chunking by available workspace (host-constant -> deterministic)
    auto need_bytes = [](int nch) -> size_t {
        return sizeof(float) * ((size_t)NC * nch * NB * NO +   // part
                                (size_t)NR * NB * NI +         // xT
                                2 * (size_t)NR * NC +          // bbuf, cbuf
                                (size_t)NC * NB * NO);         // vbuf
    };
    int nchunk = (ws_size >= need_bytes(64)) ? 64 : 32;
    int rch = NR / nchunk;

    float* part = (float*)d_ws;                              // NC*nchunk*NB*NO
    float* xT   = part + (size_t)NC * nchunk * NB * NO;      // NR*NB*NI
    float* bbuf = xT + (size_t)NR * NB * NI;                 // NR*NC
    float* cbuf = bbuf + (size_t)NR * NC;                    // NR*NC
    float* vbuf = cbuf + (size_t)NR * NC;                    // NC*NB*NO

    k_init<<<(NR * NC + 255) / 256, 256, 0, stream>>>(bbuf, cbuf);
    k_transpose<<<NR, 256, 0, stream>>>(x, xT);

    dim3 gpart(NC, nchunk);
    dim3 gagree(NC, nchunk);
    int  gred = (NC * NB * NO) / 256;   // 160 blocks

    for (int it = 0; it < 3; ++it) {
        k_partial<<<gpart, 256, 0, stream>>>(xT, W, cbuf, part, nchunk, rch);
        k_reduce<<<gred, 256, 0, stream>>>(part, vbuf, out, nchunk, it == 2 ? 1 : 0);
        if (it < 2) {
            k_agree<<<gagree, 256, 0, stream>>>(xT, W, vbuf, bbuf, rch);
            k_softmax<<<NC, 256, 0, stream>>>(bbuf, cbuf);
        }
    }
}